// Round 6
// baseline (451.448 us; speedup 1.0000x reference)
//
#include <hip/hip_runtime.h>
#include <hip/hip_fp16.h>

// GDE func: out = MLP(relu(mean_agg(z,edges)@Wg + z@Ws + bg))
// Round 5 -> 6: GEMM geometry BM=256, wave tile 128x64 (2x MFMA per staged
// byte vs 64x64), + both-sides XOR swizzle (pre-swizzled global source col,
// XOR'd LDS read slot) to kill the 16-way ds_read_b128 bank conflict
// (SQ_LDS_BANK_CONFLICT was 1.9e7/dispatch = ~28% of gemm3 time).

typedef _Float16 f16;
typedef __attribute__((ext_vector_type(2))) _Float16 f16x2;
typedef __attribute__((ext_vector_type(8))) _Float16 f16x8;
typedef __attribute__((ext_vector_type(4))) float f32x4;

__device__ __forceinline__ void async_load16(const void* g, void* lds) {
  __builtin_amdgcn_global_load_lds(
      (const __attribute__((address_space(1))) void*)g,
      (__attribute__((address_space(3))) void*)lds, 16, 0, 0);
}

__device__ __forceinline__ float fast_tanh(float x) {
  float a = fabsf(x);
  float e = __expf(-2.0f * a);
  float r = (1.0f - e) * __builtin_amdgcn_rcpf(1.0f + e);
  return copysignf(r, x);
}

__global__ __launch_bounds__(256) void zero_kernel(int* __restrict__ p, int n) {
  int i = blockIdx.x * 256 + threadIdx.x;
  int stride = gridDim.x * 256;
  for (; i < n; i += stride) p[i] = 0;
}

// ---- CSR build ----
__global__ __launch_bounds__(256) void deg_count(const int* __restrict__ dst,
                                                 int* __restrict__ degi, int E) {
  int e = blockIdx.x * 256 + threadIdx.x;
  if (e < E) atomicAdd(&degi[dst[e]], 1);
}

__global__ __launch_bounds__(256) void scan_partial(const int* __restrict__ degi,
                                                    int* __restrict__ bsum, int N) {
  __shared__ int lds[256];
  int b = blockIdx.x, t = threadIdx.x;
  int s = 0;
#pragma unroll
  for (int j = 0; j < 4; ++j) {
    int idx = b * 1024 + t * 4 + j;
    if (idx < N) s += degi[idx];
  }
  lds[t] = s;
  __syncthreads();
  for (int off = 128; off > 0; off >>= 1) {
    if (t < off) lds[t] += lds[t + off];
    __syncthreads();
  }
  if (t == 0) bsum[b] = lds[0];
}

__global__ void scan_bsums(const int* __restrict__ bsum, int* __restrict__ boff,
                           int* __restrict__ row_start, int nb, int N) {
  if (threadIdx.x == 0 && blockIdx.x == 0) {
    int acc = 0;
    for (int i = 0; i < nb; ++i) { boff[i] = acc; acc += bsum[i]; }
    row_start[N] = acc;  // == E
  }
}

__global__ __launch_bounds__(256) void scan_final(
    const int* __restrict__ degi, const int* __restrict__ boff,
    int* __restrict__ row_start, int* __restrict__ cursor, int N) {
  __shared__ int lds[256];
  int b = blockIdx.x, t = threadIdx.x;
  int base = b * 1024;
  int v[4];
  int s = 0;
#pragma unroll
  for (int j = 0; j < 4; ++j) {
    int idx = base + t * 4 + j;
    v[j] = (idx < N) ? degi[idx] : 0;
    s += v[j];
  }
  lds[t] = s;
  __syncthreads();
  for (int off = 1; off < 256; off <<= 1) {
    int x = lds[t];
    int y = (t >= off) ? lds[t - off] : 0;
    __syncthreads();
    lds[t] = x + y;
    __syncthreads();
  }
  int pre = boff[b] + lds[t] - s;
#pragma unroll
  for (int j = 0; j < 4; ++j) {
    int idx = base + t * 4 + j;
    if (idx < N) { row_start[idx] = pre; cursor[idx] = pre; pre += v[j]; }
  }
}

__global__ __launch_bounds__(256) void fill_adj(const int* __restrict__ src,
                                                const int* __restrict__ dst,
                                                int* __restrict__ cursor,
                                                int* __restrict__ adj, int E) {
  int e = blockIdx.x * 256 + threadIdx.x;
  if (e >= E) return;
  int p = atomicAdd(&cursor[dst[e]], 1);
  adj[p] = src[e];
}

// ---- fused gather + mean + Xcat: one 64-lane wave per node ----
__global__ __launch_bounds__(256) void gather_xcat(
    const float* __restrict__ z, const int* __restrict__ row_start,
    const int* __restrict__ adj, f16* __restrict__ Xc, int N) {
  int wave = (blockIdx.x * 256 + threadIdx.x) >> 6;
  int lane = threadIdx.x & 63;
  if (wave >= N) return;
  int n = wave;
  int beg = row_start[n], end = row_start[n + 1];
  float sx = 0.0f, sy = 0.0f;
  float s1x = 0.0f, s1y = 0.0f, s2x = 0.0f, s2y = 0.0f, s3x = 0.0f, s3y = 0.0f;
  int i = beg;
  for (; i + 4 <= end; i += 4) {
    int n0 = adj[i], n1 = adj[i + 1], n2 = adj[i + 2], n3 = adj[i + 3];
    float2 v0 = *(const float2*)(z + (long long)n0 * 128 + 2 * lane);
    float2 v1 = *(const float2*)(z + (long long)n1 * 128 + 2 * lane);
    float2 v2 = *(const float2*)(z + (long long)n2 * 128 + 2 * lane);
    float2 v3 = *(const float2*)(z + (long long)n3 * 128 + 2 * lane);
    sx += v0.x; sy += v0.y;
    s1x += v1.x; s1y += v1.y;
    s2x += v2.x; s2y += v2.y;
    s3x += v3.x; s3y += v3.y;
  }
  for (; i < end; ++i) {
    float2 v = *(const float2*)(z + (long long)adj[i] * 128 + 2 * lane);
    sx += v.x; sy += v.y;
  }
  sx += s1x + s2x + s3x;
  sy += s1y + s2y + s3y;
  int dg = end - beg;
  float inv = 1.0f / (float)(dg > 1 ? dg : 1);
  long long o = (long long)n * 256;
  f16x2 m; m[0] = (f16)(sx * inv); m[1] = (f16)(sy * inv);
  *(f16x2*)(Xc + o + 2 * lane) = m;
  float2 zv = *(const float2*)(z + (long long)n * 128 + 2 * lane);
  f16x2 zc; zc[0] = (f16)zv.x; zc[1] = (f16)zv.y;
  *(f16x2*)(Xc + o + 128 + 2 * lane) = zc;
}

// ---- weight prep (Wt stored [col][K] row-major f16) ----
__global__ __launch_bounds__(256) void build_wgs(
    const float* __restrict__ Wg, const float* __restrict__ Ws, f16* __restrict__ Wt) {
  int i = blockIdx.x * 256 + threadIdx.x;
  if (i >= 128 * 256) return;
  int n = i >> 8, k = i & 255;
  float v = (k < 128) ? Wg[k * 128 + n] : Ws[(k - 128) * 128 + n];
  Wt[i] = (f16)v;
}

__global__ __launch_bounds__(256) void transpose_cast(
    const float* __restrict__ W, f16* __restrict__ Wt, int K, int N) {
  int i = blockIdx.x * 256 + threadIdx.x;
  if (i >= K * N) return;
  int n = i / K, k = i - n * K;
  Wt[i] = (f16)W[k * N + n];
}

// ---------------- MFMA GEMM: BM=256, BN in {128,256}, BK=64 ----------------
// C[M,NOUT] = act(X[M,K] @ Wt^T + bias); Wt is [NOUT][K] f16.
// Waves: 2(M) x BN/64(N); wave tile 128x64 = 8x4 frags of 16x16x32.
// Staging: global_load_lds 16B/lane into LINEAR LDS; the global source
// column is pre-swizzled (slot^row&7) and reads XOR the same involution,
// so ds_read_b128 is bank-conflict-free (rule-21 both-sides swizzle).
// X needs gridDim.x*256 rows allocated (pad rows read, never stored).
template <int K, int NOUT, int BN, int ACT, bool OUTF32>
__global__ __launch_bounds__(128 * (BN / 64)) void gemm_s(
    const f16* __restrict__ X, const f16* __restrict__ Wt,
    const float* __restrict__ bias, void* __restrict__ OutV, int M) {
  constexpr int WN = BN / 64;          // wave-grid cols (2 or 4)
  constexpr int NW = 2 * WN;           // 4 or 8 waves
  constexpr int CX = 32 / NW;          // X 8-row chunks per wave
  constexpr int CW = (BN / 8) / NW;    // W 8-row chunks per wave
  __shared__ __align__(16) f16 Xs[256 * 64];
  __shared__ __align__(16) f16 Wsh[BN * 64];

  const int tid = threadIdx.x;
  const int wid = tid >> 6, lane = tid & 63;
  const int wm = wid & 1, wn = wid >> 1;   // wn in [0, WN)
  const int lr = lane & 15, lq = lane >> 4;
  const long long m0 = (long long)blockIdx.x * 256;
  const int n0 = blockIdx.y * BN;

  f32x4 acc[8][4];
#pragma unroll
  for (int i = 0; i < 8; ++i)
#pragma unroll
    for (int j = 0; j < 4; ++j)
#pragma unroll
      for (int r = 0; r < 4; ++r) acc[i][j][r] = 0.0f;

  const int srow = lane >> 3;                 // 0..7 within 8-row chunk
  const int scol = ((lane & 7) ^ srow) * 8;   // pre-swizzled source col (f16)
  const int rxor = lr & 7;                    // read-side XOR key
  const f16* Xg = X + m0 * K;
  const f16* Wg = Wt + (long long)n0 * K;

  for (int k0 = 0; k0 < K; k0 += 64) {
#pragma unroll
    for (int c = 0; c < CX; ++c) {
      int q = wid * CX + c;                   // 8-row chunk of X tile
      async_load16(Xg + (long long)(q * 8 + srow) * K + k0 + scol, &Xs[q * 512]);
    }
#pragma unroll
    for (int c = 0; c < CW; ++c) {
      int q = wid * CW + c;                   // 8-row chunk of W tile
      async_load16(Wg + (long long)(q * 8 + srow) * K + k0 + scol, &Wsh[q * 512]);
    }
    __syncthreads();
#pragma unroll
    for (int kk = 0; kk < 64; kk += 32) {
      const int sl = (kk >> 3) + lq;          // 16B slot 0..3 / 4..7
      const int co = (sl ^ rxor) * 8;         // swizzled f16 col within row
      f16x8 a[8], b[4];
#pragma unroll
      for (int i = 0; i < 8; ++i)
        a[i] = *reinterpret_cast<const f16x8*>(&Xs[(wm * 128 + i * 16 + lr) * 64 + co]);
#pragma unroll
      for (int j = 0; j < 4; ++j)
        b[j] = *reinterpret_cast<const f16x8*>(&Wsh[(wn * 64 + j * 16 + lr) * 64 + co]);
#pragma unroll
      for (int i = 0; i < 8; ++i)
#pragma unroll
        for (int j = 0; j < 4; ++j)
          acc[i][j] = __builtin_amdgcn_mfma_f32_16x16x32_f16(a[i], b[j], acc[i][j], 0, 0, 0);
    }
    __syncthreads();
  }

#pragma unroll
  for (int i = 0; i < 8; ++i) {
#pragma unroll
    for (int j = 0; j < 4; ++j) {
      int col = n0 + wn * 64 + j * 16 + lr;
      float bv = bias[col];
#pragma unroll
      for (int r = 0; r < 4; ++r) {
        long long row = m0 + wm * 128 + i * 16 + lq * 4 + r;
        if (row < M) {
          float v = acc[i][j][r] + bv;
          if (ACT == 1) v = fmaxf(v, 0.0f);
          else if (ACT == 2) v = fast_tanh(v);
          if constexpr (OUTF32)
            ((float*)OutV)[row * NOUT + col] = v;
          else
            ((f16*)OutV)[row * NOUT + col] = (f16)v;
        }
      }
    }
  }
}

extern "C" void kernel_launch(void* const* d_in, const int* in_sizes, int n_in,
                              void* d_out, int out_size, void* d_ws, size_t ws_size,
                              hipStream_t stream) {
  const float* z  = (const float*)d_in[0];
  const int*   ei = (const int*)d_in[1];
  const float* Wg = (const float*)d_in[2];
  const float* Ws = (const float*)d_in[3];
  const float* bg = (const float*)d_in[4];
  const float* W1 = (const float*)d_in[5];
  const float* b1 = (const float*)d_in[6];
  const float* W2 = (const float*)d_in[7];
  const float* b2 = (const float*)d_in[8];
  const float* W3 = (const float*)d_in[9];
  const float* b3 = (const float*)d_in[10];

  const int Nn = in_sizes[0] / 128;
  const int E  = in_sizes[1] / 2;
  const int* src = ei;
  const int* dst = ei + E;
  const int nb = (Nn + 1023) / 1024;
  const int gm = (Nn + 255) / 256;           // 256-row tiles
  const long long Mpad = (long long)gm * 256;

  // workspace overlay (peak ~207 MB):
  //   [0, 51.2M)        Xc   (gather -> gemm1)
  //   [51.2, 76.8M)     h1   (gemm1 -> gemm2)
  //   [76.8, ~80.5M)    CSR  (build -> gather)
  //   [0, 102.4M)       h3   (gemm3 -> gemm4; overlays Xc,h1,CSR - all dead)
  //   [102.4, 204.8M)   h2   (gemm2 -> gemm3)
  //   [204.8M, ...)     prepped weights (~1.7 MB)
  char* base = (char*)d_ws;
  const size_t XCB  = (size_t)Mpad * 256 * 2;
  const size_t H1B  = (size_t)Mpad * 128 * 2;
  const size_t H3B  = (size_t)Mpad * 512 * 2;
  f16* Xc = (f16*)(base);
  f16* h1 = (f16*)(base + XCB);
  f16* h3 = (f16*)(base);
  size_t off = XCB + H1B;
  auto alloc = [&](size_t b) -> void* {
    void* p = base + off;
    off += (b + 255) & ~(size_t)255;
    return p;
  };
  int* degi      = (int*)alloc((size_t)Nn * 4);
  int* row_start = (int*)alloc((size_t)(Nn + 1) * 4);
  int* cursor    = (int*)alloc((size_t)Nn * 4);
  int* adj       = (int*)alloc((size_t)E * 4);
  int* bsum      = (int*)alloc((size_t)nb * 4);
  int* boff      = (int*)alloc((size_t)nb * 4);
  off = H3B;  // h2 starts after h3 span
  f16* h2  = (f16*)alloc((size_t)Mpad * 512 * 2);
  f16* wgs = (f16*)alloc((size_t)128 * 256 * 2);
  f16* wt1 = (f16*)alloc((size_t)512 * 128 * 2);
  f16* wt2 = (f16*)alloc((size_t)512 * 512 * 2);
  f16* wt3 = (f16*)alloc((size_t)128 * 512 * 2);

  // CSR build
  zero_kernel<<<(Nn + 255) / 256, 256, 0, stream>>>(degi, Nn);
  deg_count<<<(E + 255) / 256, 256, 0, stream>>>(dst, degi, E);
  scan_partial<<<nb, 256, 0, stream>>>(degi, bsum, Nn);
  scan_bsums<<<1, 64, 0, stream>>>(bsum, boff, row_start, nb, Nn);
  scan_final<<<nb, 256, 0, stream>>>(degi, boff, row_start, cursor, Nn);
  fill_adj<<<(E + 255) / 256, 256, 0, stream>>>(src, dst, cursor, adj, E);

  // weight prep
  build_wgs<<<(128 * 256 + 255) / 256, 256, 0, stream>>>(Wg, Ws, wgs);
  transpose_cast<<<(128 * 512 + 255) / 256, 256, 0, stream>>>(W1, wt1, 128, 512);
  transpose_cast<<<(512 * 512 + 255) / 256, 256, 0, stream>>>(W2, wt2, 512, 512);
  transpose_cast<<<(512 * 128 + 255) / 256, 256, 0, stream>>>(W3, wt3, 512, 128);

  // gather + Xcat
  {
    long long tot = (long long)Nn * 64;
    gather_xcat<<<(int)((tot + 255) / 256), 256, 0, stream>>>(z, row_start, adj, Xc, Nn);
  }

  // GEMMs: L1 (K=256,N=128), L2 (K=128,N=512), L3 (K=512,N=512), L4 (K=512,N=128)
  gemm_s<256, 128, 128, 1, false><<<dim3(gm, 1), 256, 0, stream>>>(Xc, wgs, bg, (void*)h1, Nn);
  gemm_s<128, 512, 256, 2, false><<<dim3(gm, 2), 512, 0, stream>>>(h1, wt1, b1, (void*)h2, Nn);
  gemm_s<512, 512, 256, 2, false><<<dim3(gm, 2), 512, 0, stream>>>(h2, wt2, b2, (void*)h3, Nn);
  gemm_s<512, 128, 128, 0, true><<<dim3(gm, 1), 256, 0, stream>>>(h3, wt3, b3, d_out, Nn);
}

// Round 7
// 400.522 us; speedup vs baseline: 1.1271x; 1.1271x over previous
//
#include <hip/hip_runtime.h>
#include <hip/hip_fp16.h>

// GDE func: out = MLP(relu(mean_agg(z,edges)@Wg + z@Ws + bg))
// Round 6 -> 7: T3-minimum 2-phase prefetch GEMM (stage next K-tile BEFORE
// computing current; single __syncthreads per K-step; double-buffered LDS).
// N=512 layers: 256x256 tile, 8 waves, wave tile 128x64 (MFMA-dominant).
// N=128 layers: 128x128 tile, 4 waves, wave tile 64x64, 2 blocks/CU.
// Both-sides XOR swizzle kept (verified correct R6, conflicts = 0).

typedef _Float16 f16;
typedef __attribute__((ext_vector_type(2))) _Float16 f16x2;
typedef __attribute__((ext_vector_type(8))) _Float16 f16x8;
typedef __attribute__((ext_vector_type(4))) float f32x4;

__device__ __forceinline__ void async_load16(const void* g, void* lds) {
  __builtin_amdgcn_global_load_lds(
      (const __attribute__((address_space(1))) void*)g,
      (__attribute__((address_space(3))) void*)lds, 16, 0, 0);
}

__device__ __forceinline__ float fast_tanh(float x) {
  float a = fabsf(x);
  float e = __expf(-2.0f * a);
  float r = (1.0f - e) * __builtin_amdgcn_rcpf(1.0f + e);
  return copysignf(r, x);
}

__global__ __launch_bounds__(256) void zero_kernel(int* __restrict__ p, int n) {
  int i = blockIdx.x * 256 + threadIdx.x;
  int stride = gridDim.x * 256;
  for (; i < n; i += stride) p[i] = 0;
}

// ---- CSR build ----
__global__ __launch_bounds__(256) void deg_count(const int* __restrict__ dst,
                                                 int* __restrict__ degi, int E) {
  int e = blockIdx.x * 256 + threadIdx.x;
  if (e < E) atomicAdd(&degi[dst[e]], 1);
}

__global__ __launch_bounds__(256) void scan_partial(const int* __restrict__ degi,
                                                    int* __restrict__ bsum, int N) {
  __shared__ int lds[256];
  int b = blockIdx.x, t = threadIdx.x;
  int s = 0;
#pragma unroll
  for (int j = 0; j < 4; ++j) {
    int idx = b * 1024 + t * 4 + j;
    if (idx < N) s += degi[idx];
  }
  lds[t] = s;
  __syncthreads();
  for (int off = 128; off > 0; off >>= 1) {
    if (t < off) lds[t] += lds[t + off];
    __syncthreads();
  }
  if (t == 0) bsum[b] = lds[0];
}

__global__ void scan_bsums(const int* __restrict__ bsum, int* __restrict__ boff,
                           int* __restrict__ row_start, int nb, int N) {
  if (threadIdx.x == 0 && blockIdx.x == 0) {
    int acc = 0;
    for (int i = 0; i < nb; ++i) { boff[i] = acc; acc += bsum[i]; }
    row_start[N] = acc;  // == E
  }
}

__global__ __launch_bounds__(256) void scan_final(
    const int* __restrict__ degi, const int* __restrict__ boff,
    int* __restrict__ row_start, int* __restrict__ cursor, int N) {
  __shared__ int lds[256];
  int b = blockIdx.x, t = threadIdx.x;
  int base = b * 1024;
  int v[4];
  int s = 0;
#pragma unroll
  for (int j = 0; j < 4; ++j) {
    int idx = base + t * 4 + j;
    v[j] = (idx < N) ? degi[idx] : 0;
    s += v[j];
  }
  lds[t] = s;
  __syncthreads();
  for (int off = 1; off < 256; off <<= 1) {
    int x = lds[t];
    int y = (t >= off) ? lds[t - off] : 0;
    __syncthreads();
    lds[t] = x + y;
    __syncthreads();
  }
  int pre = boff[b] + lds[t] - s;
#pragma unroll
  for (int j = 0; j < 4; ++j) {
    int idx = base + t * 4 + j;
    if (idx < N) { row_start[idx] = pre; cursor[idx] = pre; pre += v[j]; }
  }
}

__global__ __launch_bounds__(256) void fill_adj(const int* __restrict__ src,
                                                const int* __restrict__ dst,
                                                int* __restrict__ cursor,
                                                int* __restrict__ adj, int E) {
  int e = blockIdx.x * 256 + threadIdx.x;
  if (e >= E) return;
  int p = atomicAdd(&cursor[dst[e]], 1);
  adj[p] = src[e];
}

// ---- fused gather + mean + Xcat: one 64-lane wave per node ----
__global__ __launch_bounds__(256) void gather_xcat(
    const float* __restrict__ z, const int* __restrict__ row_start,
    const int* __restrict__ adj, f16* __restrict__ Xc, int N) {
  int wave = (blockIdx.x * 256 + threadIdx.x) >> 6;
  int lane = threadIdx.x & 63;
  if (wave >= N) return;
  int n = wave;
  int beg = row_start[n], end = row_start[n + 1];
  float sx = 0.0f, sy = 0.0f;
  float s1x = 0.0f, s1y = 0.0f, s2x = 0.0f, s2y = 0.0f, s3x = 0.0f, s3y = 0.0f;
  int i = beg;
  for (; i + 4 <= end; i += 4) {
    int n0 = adj[i], n1 = adj[i + 1], n2 = adj[i + 2], n3 = adj[i + 3];
    float2 v0 = *(const float2*)(z + (long long)n0 * 128 + 2 * lane);
    float2 v1 = *(const float2*)(z + (long long)n1 * 128 + 2 * lane);
    float2 v2 = *(const float2*)(z + (long long)n2 * 128 + 2 * lane);
    float2 v3 = *(const float2*)(z + (long long)n3 * 128 + 2 * lane);
    sx += v0.x; sy += v0.y;
    s1x += v1.x; s1y += v1.y;
    s2x += v2.x; s2y += v2.y;
    s3x += v3.x; s3y += v3.y;
  }
  for (; i < end; ++i) {
    float2 v = *(const float2*)(z + (long long)adj[i] * 128 + 2 * lane);
    sx += v.x; sy += v.y;
  }
  sx += s1x + s2x + s3x;
  sy += s1y + s2y + s3y;
  int dg = end - beg;
  float inv = 1.0f / (float)(dg > 1 ? dg : 1);
  long long o = (long long)n * 256;
  f16x2 m; m[0] = (f16)(sx * inv); m[1] = (f16)(sy * inv);
  *(f16x2*)(Xc + o + 2 * lane) = m;
  float2 zv = *(const float2*)(z + (long long)n * 128 + 2 * lane);
  f16x2 zc; zc[0] = (f16)zv.x; zc[1] = (f16)zv.y;
  *(f16x2*)(Xc + o + 128 + 2 * lane) = zc;
}

// ---- weight prep (Wt stored [col][K] row-major f16) ----
__global__ __launch_bounds__(256) void build_wgs(
    const float* __restrict__ Wg, const float* __restrict__ Ws, f16* __restrict__ Wt) {
  int i = blockIdx.x * 256 + threadIdx.x;
  if (i >= 128 * 256) return;
  int n = i >> 8, k = i & 255;
  float v = (k < 128) ? Wg[k * 128 + n] : Ws[(k - 128) * 128 + n];
  Wt[i] = (f16)v;
}

__global__ __launch_bounds__(256) void transpose_cast(
    const float* __restrict__ W, f16* __restrict__ Wt, int K, int N) {
  int i = blockIdx.x * 256 + threadIdx.x;
  if (i >= K * N) return;
  int n = i / K, k = i - n * K;
  Wt[i] = (f16)W[k * N + n];
}

// ------------- 2-phase prefetch MFMA GEMM (T3-minimum recipe) -------------
// C[M,NOUT] = act(X[M,K] @ Wt^T + bias); Wt is [NOUT][K] f16, BK=64.
// Wave grid WM x WN; per-wave output (MI*16) x 64 (NJ=4).
//   variant A (N=512): WM=2 WN=4 MI=8 -> BM=256 BN=256, 512 thr, 128KB LDS
//   variant B (N=128): WM=2 WN=2 MI=4 -> BM=128 BN=128, 256 thr,  64KB LDS
// Schedule per K-step: STAGE(next tile, other buffer) -> ds_read+MFMA(cur)
// -> __syncthreads (drains vmcnt: waits loads issued a full phase ago).
// Both-sides swizzle: source 16B-slot ^= row&7; reads XOR the same key.
template <int K, int NOUT, int WM, int WN, int MI, int ACT, bool OUTF32>
__global__ __launch_bounds__(WM * WN * 64) void gemm_p(
    const f16* __restrict__ X, const f16* __restrict__ Wt,
    const float* __restrict__ bias, void* __restrict__ OutV, int M) {
  constexpr int NJ = 4;
  constexpr int BM = WM * MI * 16;
  constexpr int BN = WN * NJ * 16;
  constexpr int NTHR = WM * WN * 64;
  constexpr int AB = BM * 128;            // A bytes per K-step (row=128B)
  constexpr int BB = BN * 128;
  constexpr int TB = AB + BB;
  constexpr int CA = AB / (NTHR * 16);    // A stage issues per thread
  constexpr int CB = BB / (NTHR * 16);
  constexpr int NT = K / 64;              // K-steps
  __shared__ __align__(16) char L[2 * TB];

  const int tid = threadIdx.x;
  const int wid = tid >> 6, lane = tid & 63;
  const int wm = wid / WN, wn = wid % WN;
  const int lr = lane & 15, lq = lane >> 4;
  const int rxor = lr & 7;
  const long long m0 = (long long)blockIdx.x * BM;
  const int n0 = blockIdx.y * BN;

  const f16* Ag = X + m0 * K;
  const f16* Bg = Wt + (long long)n0 * K;

  f32x4 acc[MI][NJ];
#pragma unroll
  for (int i = 0; i < MI; ++i)
#pragma unroll
    for (int j = 0; j < NJ; ++j)
#pragma unroll
      for (int r = 0; r < 4; ++r) acc[i][j][r] = 0.0f;

  // stage K-tile t into buffer d (linear LDS dest, pre-swizzled global col)
  auto STAGE = [&](int d, int k0) {
#pragma unroll
    for (int c = 0; c < CA; ++c) {
      int f = c * NTHR + tid;              // 16B unit within A tile
      int row = f >> 3, slot = f & 7;
      int ss = slot ^ (row & 7);
      async_load16(Ag + (long long)row * K + k0 + ss * 8,
                   L + d * TB + c * NTHR * 16 + wid * 1024);
    }
#pragma unroll
    for (int c = 0; c < CB; ++c) {
      int f = c * NTHR + tid;
      int row = f >> 3, slot = f & 7;
      int ss = slot ^ (row & 7);
      async_load16(Bg + (long long)row * K + k0 + ss * 8,
                   L + d * TB + AB + c * NTHR * 16 + wid * 1024);
    }
  };

  auto COMPUTE = [&](int d) {
    const char* Ab = L + d * TB;
    const char* Bb = L + d * TB + AB;
#pragma unroll
    for (int kk = 0; kk < 64; kk += 32) {
      const int co = (((kk >> 3) + lq) ^ rxor) * 16;  // swizzled byte col
      f16x8 a[MI], b[NJ];
#pragma unroll
      for (int i = 0; i < MI; ++i)
        a[i] = *reinterpret_cast<const f16x8*>(
            Ab + (wm * MI * 16 + i * 16 + lr) * 128 + co);
#pragma unroll
      for (int j = 0; j < NJ; ++j)
        b[j] = *reinterpret_cast<const f16x8*>(
            Bb + (wn * NJ * 16 + j * 16 + lr) * 128 + co);
#pragma unroll
      for (int i = 0; i < MI; ++i)
#pragma unroll
        for (int j = 0; j < NJ; ++j)
          acc[i][j] = __builtin_amdgcn_mfma_f32_16x16x32_f16(a[i], b[j], acc[i][j], 0, 0, 0);
    }
  };

  STAGE(0, 0);
  __syncthreads();           // drain prologue loads
  int cur = 0;
#pragma unroll 1
  for (int t = 0; t < NT - 1; ++t) {
    STAGE(cur ^ 1, (t + 1) * 64);   // next tile in flight during compute
    COMPUTE(cur);
    __syncthreads();                // drains vmcnt (issued one phase ago)
    cur ^= 1;
  }
  COMPUTE(cur);

#pragma unroll
  for (int i = 0; i < MI; ++i) {
#pragma unroll
    for (int j = 0; j < NJ; ++j) {
      int col = n0 + wn * NJ * 16 + j * 16 + lr;
      float bv = bias[col];
#pragma unroll
      for (int r = 0; r < 4; ++r) {
        long long row = m0 + wm * MI * 16 + i * 16 + lq * 4 + r;
        if (row < M) {
          float v = acc[i][j][r] + bv;
          if (ACT == 1) v = fmaxf(v, 0.0f);
          else if (ACT == 2) v = fast_tanh(v);
          if constexpr (OUTF32)
            ((float*)OutV)[row * NOUT + col] = v;
          else
            ((f16*)OutV)[row * NOUT + col] = (f16)v;
        }
      }
    }
  }
}

extern "C" void kernel_launch(void* const* d_in, const int* in_sizes, int n_in,
                              void* d_out, int out_size, void* d_ws, size_t ws_size,
                              hipStream_t stream) {
  const float* z  = (const float*)d_in[0];
  const int*   ei = (const int*)d_in[1];
  const float* Wg = (const float*)d_in[2];
  const float* Ws = (const float*)d_in[3];
  const float* bg = (const float*)d_in[4];
  const float* W1 = (const float*)d_in[5];
  const float* b1 = (const float*)d_in[6];
  const float* W2 = (const float*)d_in[7];
  const float* b2 = (const float*)d_in[8];
  const float* W3 = (const float*)d_in[9];
  const float* b3 = (const float*)d_in[10];

  const int Nn = in_sizes[0] / 128;
  const int E  = in_sizes[1] / 2;
  const int* src = ei;
  const int* dst = ei + E;
  const int nb = (Nn + 1023) / 1024;
  const int gm = (Nn + 255) / 256;           // 256-row tiles
  const long long Mpad = (long long)gm * 256;
  const int gm128 = (int)(Mpad / 128);       // 128-row tiles over same pad

  // workspace overlay (peak ~207 MB):
  //   [0, 51.2M)        Xc   (gather -> gemm1)
  //   [51.2, 76.8M)     h1   (gemm1 -> gemm2)
  //   [76.8, ~80.5M)    CSR  (build -> gather)
  //   [0, 102.4M)       h3   (gemm3 -> gemm4; overlays Xc,h1,CSR - all dead)
  //   [102.4, 204.8M)   h2   (gemm2 -> gemm3)
  //   [204.8M, ...)     prepped weights (~1.7 MB)
  char* base = (char*)d_ws;
  const size_t XCB  = (size_t)Mpad * 256 * 2;
  const size_t H1B  = (size_t)Mpad * 128 * 2;
  const size_t H3B  = (size_t)Mpad * 512 * 2;
  f16* Xc = (f16*)(base);
  f16* h1 = (f16*)(base + XCB);
  f16* h3 = (f16*)(base);
  size_t off = XCB + H1B;
  auto alloc = [&](size_t b) -> void* {
    void* p = base + off;
    off += (b + 255) & ~(size_t)255;
    return p;
  };
  int* degi      = (int*)alloc((size_t)Nn * 4);
  int* row_start = (int*)alloc((size_t)(Nn + 1) * 4);
  int* cursor    = (int*)alloc((size_t)Nn * 4);
  int* adj       = (int*)alloc((size_t)E * 4);
  int* bsum      = (int*)alloc((size_t)nb * 4);
  int* boff      = (int*)alloc((size_t)nb * 4);
  off = H3B;  // h2 starts after h3 span
  f16* h2  = (f16*)alloc((size_t)Mpad * 512 * 2);
  f16* wgs = (f16*)alloc((size_t)128 * 256 * 2);
  f16* wt1 = (f16*)alloc((size_t)512 * 128 * 2);
  f16* wt2 = (f16*)alloc((size_t)512 * 512 * 2);
  f16* wt3 = (f16*)alloc((size_t)128 * 512 * 2);

  // CSR build
  zero_kernel<<<(Nn + 255) / 256, 256, 0, stream>>>(degi, Nn);
  deg_count<<<(E + 255) / 256, 256, 0, stream>>>(dst, degi, E);
  scan_partial<<<nb, 256, 0, stream>>>(degi, bsum, Nn);
  scan_bsums<<<1, 64, 0, stream>>>(bsum, boff, row_start, nb, Nn);
  scan_final<<<nb, 256, 0, stream>>>(degi, boff, row_start, cursor, Nn);
  fill_adj<<<(E + 255) / 256, 256, 0, stream>>>(src, dst, cursor, adj, E);

  // weight prep
  build_wgs<<<(128 * 256 + 255) / 256, 256, 0, stream>>>(Wg, Ws, wgs);
  transpose_cast<<<(128 * 512 + 255) / 256, 256, 0, stream>>>(W1, wt1, 128, 512);
  transpose_cast<<<(512 * 512 + 255) / 256, 256, 0, stream>>>(W2, wt2, 512, 512);
  transpose_cast<<<(512 * 128 + 255) / 256, 256, 0, stream>>>(W3, wt3, 512, 128);

  // gather + Xcat
  {
    long long tot = (long long)Nn * 64;
    gather_xcat<<<(int)((tot + 255) / 256), 256, 0, stream>>>(z, row_start, adj, Xc, Nn);
  }

  // L1 (K=256,N=128) variant B; L2 (K=128,N=512) variant A;
  // L3 (K=512,N=512) variant A; L4 (K=512,N=128) variant B.
  gemm_p<256, 128, 2, 2, 4, 1, false><<<dim3(gm128, 1), 256, 0, stream>>>(Xc, wgs, bg, (void*)h1, Nn);
  gemm_p<128, 512, 2, 4, 8, 2, false><<<dim3(gm, 2), 512, 0, stream>>>(h1, wt1, b1, (void*)h2, Nn);
  gemm_p<512, 512, 2, 4, 8, 2, false><<<dim3(gm, 2), 512, 0, stream>>>(h2, wt2, b2, (void*)h3, Nn);
  gemm_p<512, 128, 2, 2, 4, 0, true><<<dim3(gm128, 1), 256, 0, stream>>>(h3, wt3, b3, d_out, Nn);
}

// Round 8
// 400.045 us; speedup vs baseline: 1.1285x; 1.0012x over previous
//
#include <hip/hip_runtime.h>
#include <hip/hip_fp16.h>

// GDE func: out = MLP(relu(mean_agg(z,edges)@Wg + z@Ws + bg))
// Round 7 -> 8: (a) static named LDS double-buffers (A0/B0/A1/B1) + unroll-2
// K-loop so alias analysis keeps prefetch loads in flight through COMPUTE;
// (b) manual `s_waitcnt vmcnt(0)` + raw s_barrier (placed after COMPUTE)
// instead of __syncthreads; (c) stage-address math hoisted out of K-loop;
// (d) gather: 32 lanes/node float4 (2 nodes/wave), 4-deep chains.

typedef _Float16 f16;
typedef __attribute__((ext_vector_type(4))) _Float16 f16x4;
typedef __attribute__((ext_vector_type(8))) _Float16 f16x8;
typedef __attribute__((ext_vector_type(4))) float f32x4;

__device__ __forceinline__ void async_load16(const void* g, void* lds) {
  __builtin_amdgcn_global_load_lds(
      (const __attribute__((address_space(1))) void*)g,
      (__attribute__((address_space(3))) void*)lds, 16, 0, 0);
}

#define VMBAR()                                         \
  do {                                                  \
    asm volatile("s_waitcnt vmcnt(0)" ::: "memory");    \
    __builtin_amdgcn_s_barrier();                       \
    __builtin_amdgcn_sched_barrier(0);                  \
  } while (0)

__device__ __forceinline__ float fast_tanh(float x) {
  float a = fabsf(x);
  float e = __expf(-2.0f * a);
  float r = (1.0f - e) * __builtin_amdgcn_rcpf(1.0f + e);
  return copysignf(r, x);
}

__global__ __launch_bounds__(256) void zero_kernel(int* __restrict__ p, int n) {
  int i = blockIdx.x * 256 + threadIdx.x;
  int stride = gridDim.x * 256;
  for (; i < n; i += stride) p[i] = 0;
}

// ---- CSR build ----
__global__ __launch_bounds__(256) void deg_count(const int* __restrict__ dst,
                                                 int* __restrict__ degi, int E) {
  int e = blockIdx.x * 256 + threadIdx.x;
  if (e < E) atomicAdd(&degi[dst[e]], 1);
}

__global__ __launch_bounds__(256) void scan_partial(const int* __restrict__ degi,
                                                    int* __restrict__ bsum, int N) {
  __shared__ int lds[256];
  int b = blockIdx.x, t = threadIdx.x;
  int s = 0;
#pragma unroll
  for (int j = 0; j < 4; ++j) {
    int idx = b * 1024 + t * 4 + j;
    if (idx < N) s += degi[idx];
  }
  lds[t] = s;
  __syncthreads();
  for (int off = 128; off > 0; off >>= 1) {
    if (t < off) lds[t] += lds[t + off];
    __syncthreads();
  }
  if (t == 0) bsum[b] = lds[0];
}

__global__ void scan_bsums(const int* __restrict__ bsum, int* __restrict__ boff,
                           int* __restrict__ row_start, int nb, int N) {
  if (threadIdx.x == 0 && blockIdx.x == 0) {
    int acc = 0;
    for (int i = 0; i < nb; ++i) { boff[i] = acc; acc += bsum[i]; }
    row_start[N] = acc;  // == E
  }
}

__global__ __launch_bounds__(256) void scan_final(
    const int* __restrict__ degi, const int* __restrict__ boff,
    int* __restrict__ row_start, int* __restrict__ cursor, int N) {
  __shared__ int lds[256];
  int b = blockIdx.x, t = threadIdx.x;
  int base = b * 1024;
  int v[4];
  int s = 0;
#pragma unroll
  for (int j = 0; j < 4; ++j) {
    int idx = base + t * 4 + j;
    v[j] = (idx < N) ? degi[idx] : 0;
    s += v[j];
  }
  lds[t] = s;
  __syncthreads();
  for (int off = 1; off < 256; off <<= 1) {
    int x = lds[t];
    int y = (t >= off) ? lds[t - off] : 0;
    __syncthreads();
    lds[t] = x + y;
    __syncthreads();
  }
  int pre = boff[b] + lds[t] - s;
#pragma unroll
  for (int j = 0; j < 4; ++j) {
    int idx = base + t * 4 + j;
    if (idx < N) { row_start[idx] = pre; cursor[idx] = pre; pre += v[j]; }
  }
}

__global__ __launch_bounds__(256) void fill_adj(const int* __restrict__ src,
                                                const int* __restrict__ dst,
                                                int* __restrict__ cursor,
                                                int* __restrict__ adj, int E) {
  int e = blockIdx.x * 256 + threadIdx.x;
  if (e >= E) return;
  int p = atomicAdd(&cursor[dst[e]], 1);
  adj[p] = src[e];
}

// ---- fused gather + mean + Xcat: 32 lanes per node (2 nodes/wave) ----
// lane covers cols 4l..4l+3 via float4 (16B/lane x 32 lanes = full 512B row).
__global__ __launch_bounds__(256) void gather_xcat(
    const float* __restrict__ z, const int* __restrict__ row_start,
    const int* __restrict__ adj, f16* __restrict__ Xc, int N) {
  int node = (blockIdx.x * 256 + threadIdx.x) >> 5;
  if (node >= N) return;
  int lane = threadIdx.x & 31;
  int beg = row_start[node], end = row_start[node + 1];
  float4 s0 = {0, 0, 0, 0}, s1 = {0, 0, 0, 0}, s2 = {0, 0, 0, 0}, s3 = {0, 0, 0, 0};
  int i = beg;
  for (; i + 4 <= end; i += 4) {
    int n0 = adj[i], n1 = adj[i + 1], n2 = adj[i + 2], n3 = adj[i + 3];
    float4 v0 = *(const float4*)(z + (long long)n0 * 128 + 4 * lane);
    float4 v1 = *(const float4*)(z + (long long)n1 * 128 + 4 * lane);
    float4 v2 = *(const float4*)(z + (long long)n2 * 128 + 4 * lane);
    float4 v3 = *(const float4*)(z + (long long)n3 * 128 + 4 * lane);
    s0.x += v0.x; s0.y += v0.y; s0.z += v0.z; s0.w += v0.w;
    s1.x += v1.x; s1.y += v1.y; s1.z += v1.z; s1.w += v1.w;
    s2.x += v2.x; s2.y += v2.y; s2.z += v2.z; s2.w += v2.w;
    s3.x += v3.x; s3.y += v3.y; s3.z += v3.z; s3.w += v3.w;
  }
  for (; i < end; ++i) {
    float4 v = *(const float4*)(z + (long long)adj[i] * 128 + 4 * lane);
    s0.x += v.x; s0.y += v.y; s0.z += v.z; s0.w += v.w;
  }
  s0.x += s1.x + s2.x + s3.x;
  s0.y += s1.y + s2.y + s3.y;
  s0.z += s1.z + s2.z + s3.z;
  s0.w += s1.w + s2.w + s3.w;
  int dg = end - beg;
  float inv = 1.0f / (float)(dg > 1 ? dg : 1);
  long long o = (long long)node * 256;
  f16x4 m;
  m[0] = (f16)(s0.x * inv); m[1] = (f16)(s0.y * inv);
  m[2] = (f16)(s0.z * inv); m[3] = (f16)(s0.w * inv);
  *(f16x4*)(Xc + o + 4 * lane) = m;
  float4 zv = *(const float4*)(z + (long long)node * 128 + 4 * lane);
  f16x4 zc;
  zc[0] = (f16)zv.x; zc[1] = (f16)zv.y; zc[2] = (f16)zv.z; zc[3] = (f16)zv.w;
  *(f16x4*)(Xc + o + 128 + 4 * lane) = zc;
}

// ---- weight prep (Wt stored [col][K] row-major f16) ----
__global__ __launch_bounds__(256) void build_wgs(
    const float* __restrict__ Wg, const float* __restrict__ Ws, f16* __restrict__ Wt) {
  int i = blockIdx.x * 256 + threadIdx.x;
  if (i >= 128 * 256) return;
  int n = i >> 8, k = i & 255;
  float v = (k < 128) ? Wg[k * 128 + n] : Ws[(k - 128) * 128 + n];
  Wt[i] = (f16)v;
}

__global__ __launch_bounds__(256) void transpose_cast(
    const float* __restrict__ W, f16* __restrict__ Wt, int K, int N) {
  int i = blockIdx.x * 256 + threadIdx.x;
  if (i >= K * N) return;
  int n = i / K, k = i - n * K;
  Wt[i] = (f16)W[k * N + n];
}

// ------- 2-phase prefetch MFMA GEMM, static dbuf + manual vm0/barrier -------
// C[M,NOUT] = act(X[M,K] @ Wt^T + bias); Wt is [NOUT][K] f16, BK=64.
//   variant A (N=512): WM=2 WN=4 MI=8 -> BM=256 BN=256, 512 thr, 128KB LDS
//   variant B (N=128): WM=2 WN=2 MI=4 -> BM=128 BN=128, 256 thr,  64KB LDS
// Named static buffers A0/B0/A1/B1 -> compiler can prove stage(next) doesn't
// alias compute(cur); barrier = manual vmcnt(0) + raw s_barrier AFTER compute
// so prefetch loads get the whole MFMA phase to land.
// Both-sides swizzle: source 16B-slot ^= row&7; reads XOR same key (R6-verified).
template <int K, int NOUT, int WM, int WN, int MI, int ACT, bool OUTF32>
__global__ __launch_bounds__(WM * WN * 64) void gemm_q(
    const f16* __restrict__ X, const f16* __restrict__ Wt,
    const float* __restrict__ bias, void* __restrict__ OutV, int M) {
  constexpr int NJ = 4;
  constexpr int BM = WM * MI * 16;
  constexpr int BN = WN * NJ * 16;
  constexpr int NTHR = WM * WN * 64;
  constexpr int CA = (BM * 128) / (NTHR * 16);  // stage issues per thread (A)
  constexpr int CB = (BN * 128) / (NTHR * 16);
  constexpr int NT = K / 64;                    // K-steps (even for all our K)
  __shared__ __align__(16) f16 A0[BM * 64], A1[BM * 64];
  __shared__ __align__(16) f16 B0[BN * 64], B1[BN * 64];

  const int tid = threadIdx.x;
  const int wid = tid >> 6, lane = tid & 63;
  const int wm = wid / WN, wn = wid % WN;
  const int lr = lane & 15, lq = lane >> 4;
  const int rxor = lr & 7;
  const long long m0 = (long long)blockIdx.x * BM;
  const int n0 = blockIdx.y * BN;

  const f16* Ag = X + m0 * K;
  const f16* Bg = Wt + (long long)n0 * K;

  // hoisted per-thread stage source offsets (f16 elements) and LDS offsets
  long long aOff[CA], bOff[CB];
#pragma unroll
  for (int c = 0; c < CA; ++c) {
    int f = c * NTHR + tid;
    int row = f >> 3, ss = (f & 7) ^ (row & 7);
    aOff[c] = (long long)row * K + ss * 8;
  }
#pragma unroll
  for (int c = 0; c < CB; ++c) {
    int f = c * NTHR + tid;
    int row = f >> 3, ss = (f & 7) ^ (row & 7);
    bOff[c] = (long long)row * K + ss * 8;
  }

  f32x4 acc[MI][NJ];
#pragma unroll
  for (int i = 0; i < MI; ++i)
#pragma unroll
    for (int j = 0; j < NJ; ++j)
#pragma unroll
      for (int r = 0; r < 4; ++r) acc[i][j][r] = 0.0f;

  auto STAGE = [&](f16* dA, f16* dB, int k0) {
#pragma unroll
    for (int c = 0; c < CA; ++c)
      async_load16(Ag + aOff[c] + k0, (char*)dA + c * NTHR * 16 + wid * 1024);
#pragma unroll
    for (int c = 0; c < CB; ++c)
      async_load16(Bg + bOff[c] + k0, (char*)dB + c * NTHR * 16 + wid * 1024);
  };

  auto COMPUTE = [&](const f16* sA, const f16* sB) {
#pragma unroll
    for (int kk = 0; kk < 64; kk += 32) {
      const int co = (((kk >> 3) + lq) ^ rxor) * 16;  // swizzled byte col
      f16x8 a[MI], b[NJ];
#pragma unroll
      for (int i = 0; i < MI; ++i)
        a[i] = *reinterpret_cast<const f16x8*>(
            (const char*)sA + (wm * MI * 16 + i * 16 + lr) * 128 + co);
#pragma unroll
      for (int j = 0; j < NJ; ++j)
        b[j] = *reinterpret_cast<const f16x8*>(
            (const char*)sB + (wn * NJ * 16 + j * 16 + lr) * 128 + co);
#pragma unroll
      for (int i = 0; i < MI; ++i)
#pragma unroll
        for (int j = 0; j < NJ; ++j)
          acc[i][j] = __builtin_amdgcn_mfma_f32_16x16x32_f16(a[i], b[j], acc[i][j], 0, 0, 0);
    }
  };

  STAGE(A0, B0, 0);
  VMBAR();
#pragma unroll 1
  for (int t = 0; t < NT; t += 2) {
    STAGE(A1, B1, (t + 1) * 64);      // prefetch next while computing cur
    COMPUTE(A0, B0);
    VMBAR();                          // loads had whole compute to land
    if (t + 2 < NT) STAGE(A0, B0, (t + 2) * 64);
    COMPUTE(A1, B1);
    if (t + 2 < NT) VMBAR();
  }

#pragma unroll
  for (int i = 0; i < MI; ++i) {
#pragma unroll
    for (int j = 0; j < NJ; ++j) {
      int col = n0 + wn * NJ * 16 + j * 16 + lr;
      float bv = bias[col];
#pragma unroll
      for (int r = 0; r < 4; ++r) {
        long long row = m0 + wm * MI * 16 + i * 16 + lq * 4 + r;
        if (row < M) {
          float v = acc[i][j][r] + bv;
          if (ACT == 1) v = fmaxf(v, 0.0f);
          else if (ACT == 2) v = fast_tanh(v);
          if constexpr (OUTF32)
            ((float*)OutV)[row * NOUT + col] = v;
          else
            ((f16*)OutV)[row * NOUT + col] = (f16)v;
        }
      }
    }
  }
}

extern "C" void kernel_launch(void* const* d_in, const int* in_sizes, int n_in,
                              void* d_out, int out_size, void* d_ws, size_t ws_size,
                              hipStream_t stream) {
  const float* z  = (const float*)d_in[0];
  const int*   ei = (const int*)d_in[1];
  const float* Wg = (const float*)d_in[2];
  const float* Ws = (const float*)d_in[3];
  const float* bg = (const float*)d_in[4];
  const float* W1 = (const float*)d_in[5];
  const float* b1 = (const float*)d_in[6];
  const float* W2 = (const float*)d_in[7];
  const float* b2 = (const float*)d_in[8];
  const float* W3 = (const float*)d_in[9];
  const float* b3 = (const float*)d_in[10];

  const int Nn = in_sizes[0] / 128;
  const int E  = in_sizes[1] / 2;
  const int* src = ei;
  const int* dst = ei + E;
  const int nb = (Nn + 1023) / 1024;
  const int gm = (Nn + 255) / 256;           // 256-row tiles
  const long long Mpad = (long long)gm * 256;
  const int gm128 = (int)(Mpad / 128);       // 128-row tiles over same pad

  // workspace overlay (peak ~207 MB):
  //   [0, 51.2M)        Xc   (gather -> gemm1)
  //   [51.2, 76.8M)     h1   (gemm1 -> gemm2)
  //   [76.8, ~80.5M)    CSR  (build -> gather)
  //   [0, 102.4M)       h3   (gemm3 -> gemm4; overlays Xc,h1,CSR - all dead)
  //   [102.4, 204.8M)   h2   (gemm2 -> gemm3)
  //   [204.8M, ...)     prepped weights (~1.7 MB)
  char* base = (char*)d_ws;
  const size_t XCB  = (size_t)Mpad * 256 * 2;
  const size_t H1B  = (size_t)Mpad * 128 * 2;
  const size_t H3B  = (size_t)Mpad * 512 * 2;
  f16* Xc = (f16*)(base);
  f16* h1 = (f16*)(base + XCB);
  f16* h3 = (f16*)(base);
  size_t off = XCB + H1B;
  auto alloc = [&](size_t b) -> void* {
    void* p = base + off;
    off += (b + 255) & ~(size_t)255;
    return p;
  };
  int* degi      = (int*)alloc((size_t)Nn * 4);
  int* row_start = (int*)alloc((size_t)(Nn + 1) * 4);
  int* cursor    = (int*)alloc((size_t)Nn * 4);
  int* adj       = (int*)alloc((size_t)E * 4);
  int* bsum      = (int*)alloc((size_t)nb * 4);
  int* boff      = (int*)alloc((size_t)nb * 4);
  off = H3B;  // h2 starts after h3 span
  f16* h2  = (f16*)alloc((size_t)Mpad * 512 * 2);
  f16* wgs = (f16*)alloc((size_t)128 * 256 * 2);
  f16* wt1 = (f16*)alloc((size_t)512 * 128 * 2);
  f16* wt2 = (f16*)alloc((size_t)512 * 512 * 2);
  f16* wt3 = (f16*)alloc((size_t)128 * 512 * 2);

  // CSR build
  zero_kernel<<<(Nn + 255) / 256, 256, 0, stream>>>(degi, Nn);
  deg_count<<<(E + 255) / 256, 256, 0, stream>>>(dst, degi, E);
  scan_partial<<<nb, 256, 0, stream>>>(degi, bsum, Nn);
  scan_bsums<<<1, 64, 0, stream>>>(bsum, boff, row_start, nb, Nn);
  scan_final<<<nb, 256, 0, stream>>>(degi, boff, row_start, cursor, Nn);
  fill_adj<<<(E + 255) / 256, 256, 0, stream>>>(src, dst, cursor, adj, E);

  // weight prep
  build_wgs<<<(128 * 256 + 255) / 256, 256, 0, stream>>>(Wg, Ws, wgs);
  transpose_cast<<<(128 * 512 + 255) / 256, 256, 0, stream>>>(W1, wt1, 128, 512);
  transpose_cast<<<(512 * 512 + 255) / 256, 256, 0, stream>>>(W2, wt2, 512, 512);
  transpose_cast<<<(512 * 128 + 255) / 256, 256, 0, stream>>>(W3, wt3, 512, 128);

  // gather + Xcat (32 lanes per node)
  {
    long long tot = (long long)Nn * 32;
    gather_xcat<<<(int)((tot + 255) / 256), 256, 0, stream>>>(z, row_start, adj, Xc, Nn);
  }

  // L1 (K=256,N=128) variant B; L2 (K=128,N=512) variant A;
  // L3 (K=512,N=512) variant A; L4 (K=512,N=128) variant B.
  gemm_q<256, 128, 2, 2, 4, 1, false><<<dim3(gm128, 1), 256, 0, stream>>>(Xc, wgs, bg, (void*)h1, Nn);
  gemm_q<128, 512, 2, 4, 8, 2, false><<<dim3(gm, 2), 512, 0, stream>>>(h1, wt1, b1, (void*)h2, Nn);
  gemm_q<512, 512, 2, 4, 8, 2, false><<<dim3(gm, 2), 512, 0, stream>>>(h2, wt2, b2, (void*)h3, Nn);
  gemm_q<512, 128, 2, 2, 4, 0, true><<<dim3(gm128, 1), 256, 0, stream>>>(h3, wt3, b3, d_out, Nn);
}